// Round 11
// baseline (1481.302 us; speedup 1.0000x reference)
//
#include <hip/hip_runtime.h>
#include <math.h>

// ---------------------------------------------------------------------------
// Problem constants
// ---------------------------------------------------------------------------
#define TE 32          // edges per block
#define NODE_DIM 240
#define NPAD 248       // f16 row stride of sN16 (plain sections at 0/64/160)

typedef _Float16 f16;
typedef f16 f16x2 __attribute__((ext_vector_type(2)));
typedef f16 f16x4 __attribute__((ext_vector_type(4)));
typedef f16 f16x8 __attribute__((ext_vector_type(8)));
typedef float f32x4 __attribute__((ext_vector_type(4)));

__device__ __forceinline__ f16x2 cvtpk(float a, float b) {
#if __has_builtin(__builtin_amdgcn_cvt_pkrtz)
    return __builtin_bit_cast(f16x2, __builtin_amdgcn_cvt_pkrtz(a, b));
#else
    f16x2 r = {(f16)a, (f16)b}; return r;
#endif
}

// PATHS = [(0,0,0),(1,1,0),(2,2,0),(0,1,1),(1,0,1),(1,2,1),
//          (2,1,1),(0,2,2),(2,0,2),(1,1,2),(2,2,2)]
// tp_w offsets: 0,16384,24576,28672,36864,40960,45056,47104,51200,52224,54272
// w3j offsets:  0,1,10,35,44,53,98,143,168,193,238 (total 363)

// ---------------------------------------------------------------------------
// Wigner-3j init kernel (exact port of the reference construction)
// ---------------------------------------------------------------------------
struct cplx { double re, im; };
__device__ inline cplx cmul(cplx a, cplx b) {
    return { a.re*b.re - a.im*b.im, a.re*b.im + a.im*b.re };
}

__device__ double dfact(int n) { double r = 1.0; for (int i = 2; i <= n; ++i) r *= i; return r; }

__device__ double su2_cg(int j1, int m1, int j2, int m2, int j3, int m3) {
    if (m3 != m1 + m2) return 0.0;
    int vmin = max(max(-j1 + j2 + m3, -j1 + m1), 0);
    int vmax = min(min(j2 + j3 + m1, j3 - j1 + j2), j3 + m3);
    double C = sqrt((2.0*j3 + 1.0) * dfact(j3 + j1 - j2) * dfact(j3 - j1 + j2) * dfact(j1 + j2 - j3)
                    * dfact(j3 + m3) * dfact(j3 - m3)
                    / (dfact(j1 + j2 + j3 + 1) * dfact(j1 - m1) * dfact(j1 + m1)
                       * dfact(j2 - m2) * dfact(j2 + m2)));
    double S = 0.0;
    for (int v = vmin; v <= vmax; ++v) {
        double sgn = ((v + j2 + m2) & 1) ? -1.0 : 1.0;
        S += sgn * dfact(j2 + j3 + m1 - v) * dfact(j1 - m1 + v)
             / (dfact(v) * dfact(j3 - j1 + j2 - v) * dfact(j3 + m3 - v) * dfact(v + j1 - j2 - m3));
    }
    return C * S;
}

__device__ cplx rtc(int l, int a, int b) {
    double re = 0.0, im = 0.0;
    const double inv_s2 = 0.70710678118654752440;
    int m = a - l;
    if (m < 0) {
        if (b == l - m)      re = inv_s2;
        else if (b == l + m) im = -inv_s2;
    } else if (m == 0) {
        if (b == l) re = 1.0;
    } else {
        double s = (m & 1) ? -1.0 : 1.0;
        if (b == l + m)      re = s * inv_s2;
        else if (b == l - m) im = s * inv_s2;
    }
    if (l == 1) { double t = re; re = im; im = -t; }
    else if (l == 2) { re = -re; im = -im; }
    return { re, im };
}

__global__ void w3j_init(float* __restrict__ out) {
    __shared__ double sRe[363], sIm[363];
    __shared__ double sNorm[11];
    __shared__ int    sUse[11];
    const int L1A[11] = {0,1,2,0,1,1,2,0,2,1,2};
    const int L2A[11] = {0,1,2,1,0,2,1,2,0,1,2};
    const int L3A[11] = {0,0,0,1,1,1,1,2,2,2,2};
    const int OFF[12] = {0,1,10,35,44,53,98,143,168,193,238,363};
    int t = threadIdx.x;
    if (t < 363) {
        int p = 0;
        while (p < 10 && t >= OFF[p+1]) ++p;
        int rel = t - OFF[p];
        int a1 = L1A[p], a2 = L2A[p], a3 = L3A[p];
        int n1 = 2*a1 + 1, n2 = 2*a2 + 1, n3 = 2*a3 + 1;
        int jj = rel / (n2*n3), ll = (rel / n3) % n2, mm = rel % n3;
        double cr = 0.0, ci = 0.0;
        for (int i = 0; i < n1; ++i)
            for (int k = 0; k < n2; ++k)
                for (int n = 0; n < n3; ++n) {
                    double c = su2_cg(a1, i - a1, a2, k - a2, a3, n - a3);
                    if (c == 0.0) continue;
                    cplx q1 = rtc(a1, i, jj);
                    cplx q2 = rtc(a2, k, ll);
                    cplx q3 = rtc(a3, n, mm); q3.im = -q3.im;
                    cplx pr = cmul(cmul(q1, q2), q3);
                    cr += pr.re * c; ci += pr.im * c;
                }
        sRe[t] = cr; sIm[t] = ci;
    }
    __syncthreads();
    if (t < 11) {
        double nr = 0.0, ni = 0.0;
        for (int e = OFF[t]; e < OFF[t+1]; ++e) { nr += sRe[e]*sRe[e]; ni += sIm[e]*sIm[e]; }
        int use_im = (sqrt(nr) < 1e-8) ? 1 : 0;
        sUse[t] = use_im;
        sNorm[t] = sqrt(use_im ? ni : nr);
    }
    __syncthreads();
    if (t < 363) {
        int p = 0;
        while (p < 10 && t >= OFF[p+1]) ++p;
        out[t] = (float)((sUse[p] ? sIm[t] : sRe[t]) / sNorm[p]);
    }
}

// ---------------------------------------------------------------------------
// Weight prep (verified r7/r8): tp_w (f32) -> f16, alpha folded, per-lane
// fragment order. Fragment blocks of 512 f16 (one 32k x 16n MFMA B tile),
// f = ks*NT + nt; element lane*8+jj = W[k=ks*32+(lane>>4)*8+jj][n=nt*16+(lane&15)].
// ---------------------------------------------------------------------------
__global__ void w_prep(const float* __restrict__ tp_w, f16* __restrict__ wpre) {
    const int WOFF[11] = {0,16384,24576,28672,36864,40960,45056,47104,51200,52224,54272};
    const int UA[11]   = {64,32,16,64,32,32,16,64,16,32,16};
    const int NA[11]   = {64,64,64,32,32,32,32,16,16,16,16};
    const int L3A[11]  = {0,0,0,1,1,1,1,2,2,2,2};
    const float alph[3] = { 1.0f/sqrtf(448.0f), 1.0f/24.0f, 1.0f/sqrtf(512.0f) };
    int tid = threadIdx.x;
    for (int p = 0; p < 11; ++p) {
        int U = UA[p], N = NA[p], woff = WOFF[p];
        int NT = N/16;
        int size = U*4*N;
        float alpha = alph[L3A[p]];
        for (int j = tid; j < size; j += 256) {
            int f = j >> 9, r = j & 511;                // 512 f16 per fragment block
            int lane = r >> 3, jj = r & 7;              // lane 0..63
            int ks = f / NT, nt = f - ks*NT;
            int k = ks*32 + (lane>>4)*8 + jj;           // global (u*4+v) row
            int n = nt*16 + (lane&15);
            wpre[woff + j] = (f16)(tp_w[woff + k*N + n] * alpha);
        }
    }
}

// ---------------------------------------------------------------------------
// Cooperative B-table build for one l1>=1 path:
//   B[e*NK+kk][u] = sum_i n[e, SEC + u*NI + i] * cy[e,i,kk]
// Row stride UP = U+2 (odd bank stride -> ~2-way free on consume).
// cy computed in the builder thread's registers (TE*NK <= 160 threads active).
// ---------------------------------------------------------------------------
template<int l1, int l2, int l3>
__device__ __forceinline__ void build_B(
    int tid, int cgoff, f16* B,
    const f16* sN16, const float (*sY)[8], const float* sW3)
{
    constexpr int U  = (l1 == 1) ? 32 : 16;
    constexpr int NI = 2*l1 + 1, NJ = 2*l2 + 1, NK = 2*l3 + 1;
    constexpr int SEC = (l1 == 1) ? 64 : 160;
    constexpr int UP = U + 2;

    for (int idx = tid; idx < TE*NK; idx += 256) {
        int e = idx / NK, kk = idx - e*NK;
        float cyr[NI];
        #pragma unroll
        for (int i = 0; i < NI; ++i) {
            float c = 0.f;
            #pragma unroll
            for (int j = 0; j < NJ; ++j) {
                float yj = (l2 == 0) ? 1.f : ((l2 == 1) ? sY[e][j] : sY[e][3 + j]);
                c += sW3[cgoff + (i*NJ + j)*NK + kk] * yj;
            }
            cyr[i] = c;
        }
        const f16* nb = sN16 + e*NPAD + SEC;
        f16* brow = B + idx*UP;
        #pragma unroll 4
        for (int u = 0; u < U; ++u) {
            float b = 0.f;
            #pragma unroll
            for (int i = 0; i < NI; ++i) b += (float)nb[u*NI + i] * cyr[i];
            brow[u] = (f16)b;
        }
    }
}

// ---------------------------------------------------------------------------
// MFMA loop for an l1>=1 path consuming its B-table. Task map = r8-verified:
//   task = t*4+wv; nt = wv%NT; mt = task/NT; kk = mt>>1; e = (mt&1)*16+ln.
// Per ks: one shared W fragment; per task: one f16x2 B read + 4 pk-muls.
// ---------------------------------------------------------------------------
template<int l1, int l2, int l3>
__device__ __forceinline__ void mfma_B(
    int tid, int woff,
    const f16* __restrict__ wpre, const f16* B,
    const f16x2 (*sWlPk)[6],
    f32x4 (&acc)[3])
{
    constexpr int U  = (l1 == 1) ? 32 : 16;
    constexpr int N  = (l3 == 0) ? 64 : (l3 == 1) ? 32 : 16;
    constexpr int NK = 2*l3 + 1;
    constexpr int M  = NK * TE;
    constexpr int KS = U / 8;
    constexpr int NT = N / 16;
    constexpr int NTASKS = (M/16) * NT;
    constexpr int NW = (NTASKS + 3) / 4;
    constexpr int UP = U + 2;

    const int wv = tid >> 6, lane = tid & 63;
    const int ln = tid & 15, qt = (tid & 63) >> 4;
    const int ntw = wv % NT;

    const f16* browT[NW];
    f16x2 wl0T[NW], wl1T[NW];
    #pragma unroll
    for (int t = 0; t < NW; ++t) {
        int task = t*4 + wv;
        if (task < NTASKS) {
            int mt = task / NT;
            int kk = mt >> 1;
            int e  = (mt & 1)*16 + ln;
            browT[t] = B + (e*NK + kk)*UP;
            wl0T[t] = sWlPk[e][l2*2 + 0];
            wl1T[t] = sWlPk[e][l2*2 + 1];
        }
    }

    const f16* wbase = wpre + woff + (size_t)ntw*512 + lane*8;
    #pragma unroll
    for (int ks = 0; ks < KS; ++ks) {
        f16x8 wf = *(const f16x8*)(wbase + (size_t)ks*NT*512);
        const int u0 = ks*8 + qt*2;
        #pragma unroll
        for (int t = 0; t < NW; ++t) {
            int task = t*4 + wv;
            if (task < NTASKS) {
                f16x2 bh = *(const f16x2*)(browT[t] + u0);
                f16x2 b00 = {bh[0], bh[0]}, b11 = {bh[1], bh[1]};
                f16x2 a01 = b00*wl0T[t], a23 = b00*wl1T[t];
                f16x2 a45 = b11*wl0T[t], a67 = b11*wl1T[t];
                f16x8 af = {a01[0],a01[1],a23[0],a23[1],a45[0],a45[1],a67[0],a67[1]};
                acc[t] = __builtin_amdgcn_mfma_f32_16x16x32_f16(af, wf, acc[t], 0, 0, 0);
            }
        }
    }
}

// l1 == 0 path (NI=1): b = n[e,u] directly from sN16's l0 section (r8-verified).
template<int l2, int l3>
__device__ __forceinline__ void mfma_l0(
    int tid, int woff, int cgoff,
    const f16* __restrict__ wpre,
    const f16* sN16, const float (*sY)[8], const float* sW3,
    const f16x2 (*sWlPk)[6],
    f32x4 (&acc)[3])
{
    constexpr int N  = (l3 == 0) ? 64 : (l3 == 1) ? 32 : 16;
    constexpr int NJ = 2*l2 + 1, NK = 2*l3 + 1;
    constexpr int M  = NK * TE;
    constexpr int KS = 8;                        // U = 64
    constexpr int NT = N / 16;
    constexpr int NTASKS = (M/16) * NT;
    constexpr int NW = (NTASKS + 3) / 4;

    const int wv = tid >> 6, lane = tid & 63;
    const int ln = tid & 15, qt = (tid & 63) >> 4;
    const int ntw = wv % NT;

    const f16* nbT[NW];
    f16x2 cyP[NW];
    f16x2 wl0T[NW], wl1T[NW];
    #pragma unroll
    for (int t = 0; t < NW; ++t) {
        int task = t*4 + wv;
        if (task < NTASKS) {
            int mt = task / NT;
            int kk = mt >> 1;
            int e  = (mt & 1)*16 + ln;
            float c = 0.f;
            #pragma unroll
            for (int j = 0; j < NJ; ++j) {
                float yj = (l2 == 0) ? 1.f : ((l2 == 1) ? sY[e][j] : sY[e][3 + j]);
                c += sW3[cgoff + j*NK + kk] * yj;
            }
            cyP[t] = cvtpk(c, c);
            wl0T[t] = sWlPk[e][l2*2 + 0];
            wl1T[t] = sWlPk[e][l2*2 + 1];
            nbT[t]  = sN16 + e*NPAD;             // SEC = 0
        }
    }

    const f16* wbase = wpre + woff + (size_t)ntw*512 + lane*8;
    #pragma unroll
    for (int ks = 0; ks < KS; ++ks) {
        f16x8 wf = *(const f16x8*)(wbase + (size_t)ks*NT*512);
        const int u0 = ks*8 + qt*2;
        #pragma unroll
        for (int t = 0; t < NW; ++t) {
            int task = t*4 + wv;
            if (task < NTASKS) {
                f16x2 n01 = *(const f16x2*)(nbT[t] + u0);
                f16x2 bh = n01 * cyP[t];
                f16x2 b00 = {bh[0], bh[0]}, b11 = {bh[1], bh[1]};
                f16x2 a01 = b00*wl0T[t], a23 = b00*wl1T[t];
                f16x2 a45 = b11*wl0T[t], a67 = b11*wl1T[t];
                f16x8 af = {a01[0],a01[1],a23[0],a23[1],a45[0],a45[1],a67[0],a67[1]};
                acc[t] = __builtin_amdgcn_mfma_f32_16x16x32_f16(af, wf, acc[t], 0, 0, 0);
            }
        }
    }
}

// Direct accumulator -> global store (alpha in wpre, mask in wl; f32, no staging).
// D layout (verified r5/r7/r8): col = lane&15, row = 4*(lane>>4) + reg.
template<int NK, int NT, int NTASKS, int OFF>
__device__ __forceinline__ void store_direct(int tid, const f32x4 (&acc)[3],
                                             float* __restrict__ out, long eg0)
{
    int wv = tid >> 6;
    int ln = tid & 15, qt = (tid & 63) >> 4;
    #pragma unroll
    for (int t = 0; t < 3; ++t) {
        int task = t*4 + wv;
        if (task < NTASKS) {
            int mt = task / NT, nt = task % NT;
            int kk = mt >> 1;
            int e0 = (mt & 1) * 16;
            int ch = OFF + (nt*16 + ln)*NK + kk;
            #pragma unroll
            for (int r = 0; r < 4; ++r) {
                int e = e0 + qt*4 + r;
                __builtin_nontemporal_store(acc[t][r], out + (eg0 + e)*NODE_DIM + ch);
            }
        }
    }
}

__global__ __launch_bounds__(256, 4)
void edge_main(const float* __restrict__ node_feat,
               const int*   __restrict__ edge_src,
               const float* __restrict__ edge_vec,
               const float* __restrict__ maskp,
               const float* __restrict__ mlp_w1, const float* __restrict__ mlp_b1,
               const float* __restrict__ mlp_w2, const float* __restrict__ mlp_b2,
               const f16*   __restrict__ wpre,
               const float* __restrict__ w3j,
               float* __restrict__ out)
{
    __shared__ __align__(16) f16 sN16[TE*NPAD];     // 15.5KB node rows
    __shared__ __align__(16) f16 Bls[8256];         // 16.1KB B-tables (per group)
    __shared__ float sW3[364];
    __shared__ float sY[TE][8];
    __shared__ f16x2 sWlPk[TE][6];

    // phase-0 scratch aliases onto Bls (10.1KB used; dead before first build)
    float* sRbf  = (float*)Bls;             // [TE][32]  4KB
    float* sH    = sRbf + TE*32;            // [TE][32]  4KB
    float* sWl   = sH   + TE*32;            // [TE][12]  1.5KB
    float* sR    = sWl  + TE*12;            // [TE]
    float* sRb2  = sR   + TE;               // [TE]
    float* sMask = sRb2 + TE;               // [TE]
    int*   sSrc  = (int*)(sMask + TE);      // [TE]

    int tid = threadIdx.x;
    long eg0 = (long)blockIdx.x * TE;

    // ---- phase 0a: per-edge geometry + zero node rows --------------------
    if (tid < TE) {
        long eg = eg0 + tid;
        float vx = edge_vec[eg*3 + 0], vy = edge_vec[eg*3 + 1], vz = edge_vec[eg*3 + 2];
        float rn = sqrtf(vx*vx + vy*vy + vz*vz);
        float r  = fmaxf(rn, 1e-12f);
        float inv = 1.0f / r;
        float x = vx*inv, y = vy*inv, z = vz*inv;
        sR[tid] = r;
        float rb = 0.5f * (cosf(r * 3.14159265358979323846f / 5.0f) + 1.0f);
        sRb2[tid] = (r < 5.0f) ? rb*rb : 0.0f;
        sMask[tid] = maskp[eg];
        sSrc[tid]  = edge_src[eg];
        const float s3 = sqrtf(3.0f), s5 = sqrtf(5.0f), s15 = sqrtf(15.0f);
        sY[tid][0] = s3*x; sY[tid][1] = s3*y; sY[tid][2] = s3*z;
        sY[tid][3] = s15*x*z;
        sY[tid][4] = s15*x*y;
        sY[tid][5] = s5*(y*y - 0.5f*(x*x + z*z));
        sY[tid][6] = s15*y*z;
        sY[tid][7] = 0.5f*s15*(z*z - x*x);
    }
    for (int idx = tid; idx < TE*(NPAD/8); idx += 256) {   // zero incl. row pads
        f16x8 z = {0,0,0,0,0,0,0,0};
        *(f16x8*)&sN16[idx*8] = z;
    }
    for (int t = tid; t < 363; t += 256) sW3[t] = w3j[t];   // grid-stride (363 > 256)
    __syncthreads();

    // ---- phase 0b: gather node rows (f32 float4 -> f16 LDS) + RBF --------
    {
        float em5  = expf(-5.0f);
        float step = (1.0f - em5) / 31.0f;
        float beta = 256.0f / ((1.0f - em5) * (1.0f - em5));
        for (int idx = tid; idx < TE*32; idx += 256) {
            int e = idx >> 5, j = idx & 31;
            float mean = em5 + step * j;
            float d = expf(-sR[e]) - mean;
            sRbf[e*32 + j] = sRb2[e] * expf(-beta * d * d);
        }
    }
    for (int idx = tid; idx < TE*60; idx += 256) {
        int e = idx / 60, q = idx - e*60;
        f32x4 v = *(const f32x4*)(node_feat + (long)sSrc[e]*NODE_DIM + q*4);
        f16x4 h = {(f16)v.x, (f16)v.y, (f16)v.z, (f16)v.w};
        *(f16x4*)&sN16[e*NPAD + q*4] = h;
    }
    __syncthreads();

    // ---- phase 0c: per-l MLP -> edge weights wl (mask folded in) ---------
    for (int l = 0; l < 3; ++l) {
        for (int idx = tid; idx < TE*32; idx += 256) {
            int e = idx >> 5, j = idx & 31;
            float zacc = mlp_b1[l*32 + j];
            #pragma unroll 8
            for (int rr = 0; rr < 32; ++rr) zacc += sRbf[e*32 + rr] * mlp_w1[(l*32 + rr)*32 + j];
            sH[e*32 + j] = zacc / (1.0f + expf(-zacc));   // silu
        }
        __syncthreads();
        for (int idx = tid; idx < TE*4; idx += 256) {
            int e = idx >> 2, v = idx & 3;
            float zacc = mlp_b2[l*4 + v];
            #pragma unroll 8
            for (int j = 0; j < 32; ++j) zacc += sH[e*32 + j] * mlp_w2[(l*32 + j)*4 + v];
            sWl[e*12 + l*4 + v] = zacc;
        }
        __syncthreads();
    }
    // pack (wl * mask) as f16 pairs
    for (int idx = tid; idx < TE*6; idx += 256) {
        int e = idx / 6, h = idx - e*6;
        int l = h >> 1, vh = h & 1;
        float m = sMask[e];
        f16x2 p = {(f16)(sWl[e*12 + l*4 + vh*2] * m), (f16)(sWl[e*12 + l*4 + vh*2 + 1] * m)};
        sWlPk[e][h] = p;
    }
    __syncthreads();    // scratch (aliased on Bls) dead from here

    f32x4 acc[3];

    // ---- group l3=0: paths 000 (direct), 110, 220 (B) --------------------
    build_B<1,1,0>(tid,   1, Bls,        sN16, sY, sW3);   // 32 rows x 34
    build_B<2,2,0>(tid,  10, Bls + 1088, sN16, sY, sW3);   // 32 rows x 18
    __syncthreads();
    #pragma unroll
    for (int t = 0; t < 3; ++t) acc[t] = {0.f, 0.f, 0.f, 0.f};
    mfma_l0<0,0>(tid,     0,   0, wpre, sN16, sY, sW3, sWlPk, acc);
    mfma_B<1,1,0>(tid, 16384, wpre, Bls,        sWlPk, acc);
    mfma_B<2,2,0>(tid, 24576, wpre, Bls + 1088, sWlPk, acc);
    store_direct<1, 4, 8, 0>(tid, acc, out, eg0);
    __syncthreads();    // B consumed by all waves before group-1 rebuild

    // ---- group l3=1: paths 011 (direct), 101, 121, 211 (B) ---------------
    build_B<1,0,1>(tid,  44, Bls,        sN16, sY, sW3);   // 96 x 34
    build_B<1,2,1>(tid,  53, Bls + 3264, sN16, sY, sW3);   // 96 x 34
    build_B<2,1,1>(tid,  98, Bls + 6528, sN16, sY, sW3);   // 96 x 18
    __syncthreads();
    #pragma unroll
    for (int t = 0; t < 3; ++t) acc[t] = {0.f, 0.f, 0.f, 0.f};
    mfma_l0<1,1>(tid, 28672,  35, wpre, sN16, sY, sW3, sWlPk, acc);
    mfma_B<1,0,1>(tid, 36864, wpre, Bls,        sWlPk, acc);
    mfma_B<1,2,1>(tid, 40960, wpre, Bls + 3264, sWlPk, acc);
    mfma_B<2,1,1>(tid, 45056, wpre, Bls + 6528, sWlPk, acc);
    store_direct<3, 2, 12, 64>(tid, acc, out, eg0);

    // ---- group l3=2: 022 (direct), then 202, 112, 222 sequential B -------
    #pragma unroll
    for (int t = 0; t < 3; ++t) acc[t] = {0.f, 0.f, 0.f, 0.f};
    mfma_l0<2,2>(tid, 47104, 143, wpre, sN16, sY, sW3, sWlPk, acc);
    __syncthreads();    // group-1 B consumed
    build_B<2,0,2>(tid, 168, Bls, sN16, sY, sW3);          // 160 x 18
    __syncthreads();
    mfma_B<2,0,2>(tid, 51200, wpre, Bls, sWlPk, acc);
    __syncthreads();
    build_B<1,1,2>(tid, 193, Bls, sN16, sY, sW3);          // 160 x 34
    __syncthreads();
    mfma_B<1,1,2>(tid, 52224, wpre, Bls, sWlPk, acc);
    __syncthreads();
    build_B<2,2,2>(tid, 238, Bls, sN16, sY, sW3);          // 160 x 18
    __syncthreads();
    mfma_B<2,2,2>(tid, 54272, wpre, Bls, sWlPk, acc);
    store_direct<5, 1, 10, 160>(tid, acc, out, eg0);
}

// ---------------------------------------------------------------------------
// launch
// ---------------------------------------------------------------------------
extern "C" void kernel_launch(void* const* d_in, const int* in_sizes, int n_in,
                              void* d_out, int out_size, void* d_ws, size_t ws_size,
                              hipStream_t stream)
{
    const float* node_feat = (const float*)d_in[0];
    const int*   edge_idx  = (const int*)  d_in[1];
    const float* edge_vec  = (const float*)d_in[2];
    const float* maskp     = (const float*)d_in[3];
    const float* mlp_w1    = (const float*)d_in[4];
    const float* mlp_b1    = (const float*)d_in[5];
    const float* mlp_w2    = (const float*)d_in[6];
    const float* mlp_b2    = (const float*)d_in[7];
    const float* tp_w      = (const float*)d_in[8];
    float* out  = (float*)d_out;
    float* w3j  = (float*)d_ws;
    f16*   wpre = (f16*)((char*)d_ws + 2048);     // 110592 B of f16 weights

    int E = in_sizes[3];                 // = N_EDGES = 800000 (divisible by TE)
    const int* edge_src = edge_idx;      // row 0 of (2, E)

    hipLaunchKernelGGL(w3j_init, dim3(1), dim3(512), 0, stream, w3j);
    hipLaunchKernelGGL(w_prep,   dim3(1), dim3(256), 0, stream, tp_w, wpre);
    hipLaunchKernelGGL(edge_main, dim3(E / TE), dim3(256), 0, stream,
                       node_feat, edge_src, edge_vec, maskp,
                       mlp_w1, mlp_b1, mlp_w2, mlp_b2, wpre, w3j, out);
}

// Round 12
// 1224.681 us; speedup vs baseline: 1.2095x; 1.2095x over previous
//
#include <hip/hip_runtime.h>
#include <math.h>

// ---------------------------------------------------------------------------
// Problem constants
// ---------------------------------------------------------------------------
#define TE 32          // edges per block
#define NODE_DIM 240
#define NPAD 244       // f16 row stride of sN16 (488B: dword stride 122 == 26 mod 32 -> 2-way free)

typedef _Float16 f16;
typedef f16 f16x2 __attribute__((ext_vector_type(2)));
typedef f16 f16x4 __attribute__((ext_vector_type(4)));
typedef f16 f16x8 __attribute__((ext_vector_type(8)));
typedef float f32x4 __attribute__((ext_vector_type(4)));

__device__ __forceinline__ f16x2 cvtpk(float a, float b) {
#if __has_builtin(__builtin_amdgcn_cvt_pkrtz)
    return __builtin_bit_cast(f16x2, __builtin_amdgcn_cvt_pkrtz(a, b));
#else
    f16x2 r = {(f16)a, (f16)b}; return r;
#endif
}

// PATHS = [(0,0,0),(1,1,0),(2,2,0),(0,1,1),(1,0,1),(1,2,1),
//          (2,1,1),(0,2,2),(2,0,2),(1,1,2),(2,2,2)]
// tp_w offsets: 0,16384,24576,28672,36864,40960,45056,47104,51200,52224,54272
// w3j offsets:  0,1,10,35,44,53,98,143,168,193,238 (total 363)

// ---------------------------------------------------------------------------
// Wigner-3j init kernel (exact port of the reference construction)
// ---------------------------------------------------------------------------
struct cplx { double re, im; };
__device__ inline cplx cmul(cplx a, cplx b) {
    return { a.re*b.re - a.im*b.im, a.re*b.im + a.im*b.re };
}

__device__ double dfact(int n) { double r = 1.0; for (int i = 2; i <= n; ++i) r *= i; return r; }

__device__ double su2_cg(int j1, int m1, int j2, int m2, int j3, int m3) {
    if (m3 != m1 + m2) return 0.0;
    int vmin = max(max(-j1 + j2 + m3, -j1 + m1), 0);
    int vmax = min(min(j2 + j3 + m1, j3 - j1 + j2), j3 + m3);
    double C = sqrt((2.0*j3 + 1.0) * dfact(j3 + j1 - j2) * dfact(j3 - j1 + j2) * dfact(j1 + j2 - j3)
                    * dfact(j3 + m3) * dfact(j3 - m3)
                    / (dfact(j1 + j2 + j3 + 1) * dfact(j1 - m1) * dfact(j1 + m1)
                       * dfact(j2 - m2) * dfact(j2 + m2)));
    double S = 0.0;
    for (int v = vmin; v <= vmax; ++v) {
        double sgn = ((v + j2 + m2) & 1) ? -1.0 : 1.0;
        S += sgn * dfact(j2 + j3 + m1 - v) * dfact(j1 - m1 + v)
             / (dfact(v) * dfact(j3 - j1 + j2 - v) * dfact(j3 + m3 - v) * dfact(v + j1 - j2 - m3));
    }
    return C * S;
}

__device__ cplx rtc(int l, int a, int b) {
    double re = 0.0, im = 0.0;
    const double inv_s2 = 0.70710678118654752440;
    int m = a - l;
    if (m < 0) {
        if (b == l - m)      re = inv_s2;
        else if (b == l + m) im = -inv_s2;
    } else if (m == 0) {
        if (b == l) re = 1.0;
    } else {
        double s = (m & 1) ? -1.0 : 1.0;
        if (b == l + m)      re = s * inv_s2;
        else if (b == l - m) im = s * inv_s2;
    }
    if (l == 1) { double t = re; re = im; im = -t; }
    else if (l == 2) { re = -re; im = -im; }
    return { re, im };
}

__global__ void w3j_init(float* __restrict__ out) {
    __shared__ double sRe[363], sIm[363];
    __shared__ double sNorm[11];
    __shared__ int    sUse[11];
    const int L1A[11] = {0,1,2,0,1,1,2,0,2,1,2};
    const int L2A[11] = {0,1,2,1,0,2,1,2,0,1,2};
    const int L3A[11] = {0,0,0,1,1,1,1,2,2,2,2};
    const int OFF[12] = {0,1,10,35,44,53,98,143,168,193,238,363};
    int t = threadIdx.x;
    if (t < 363) {
        int p = 0;
        while (p < 10 && t >= OFF[p+1]) ++p;
        int rel = t - OFF[p];
        int a1 = L1A[p], a2 = L2A[p], a3 = L3A[p];
        int n1 = 2*a1 + 1, n2 = 2*a2 + 1, n3 = 2*a3 + 1;
        int jj = rel / (n2*n3), ll = (rel / n3) % n2, mm = rel % n3;
        double cr = 0.0, ci = 0.0;
        for (int i = 0; i < n1; ++i)
            for (int k = 0; k < n2; ++k)
                for (int n = 0; n < n3; ++n) {
                    double c = su2_cg(a1, i - a1, a2, k - a2, a3, n - a3);
                    if (c == 0.0) continue;
                    cplx q1 = rtc(a1, i, jj);
                    cplx q2 = rtc(a2, k, ll);
                    cplx q3 = rtc(a3, n, mm); q3.im = -q3.im;
                    cplx pr = cmul(cmul(q1, q2), q3);
                    cr += pr.re * c; ci += pr.im * c;
                }
        sRe[t] = cr; sIm[t] = ci;
    }
    __syncthreads();
    if (t < 11) {
        double nr = 0.0, ni = 0.0;
        for (int e = OFF[t]; e < OFF[t+1]; ++e) { nr += sRe[e]*sRe[e]; ni += sIm[e]*sIm[e]; }
        int use_im = (sqrt(nr) < 1e-8) ? 1 : 0;
        sUse[t] = use_im;
        sNorm[t] = sqrt(use_im ? ni : nr);
    }
    __syncthreads();
    if (t < 363) {
        int p = 0;
        while (p < 10 && t >= OFF[p+1]) ++p;
        out[t] = (float)((sUse[p] ? sIm[t] : sRe[t]) / sNorm[p]);
    }
}

// ---------------------------------------------------------------------------
// Weight prep (verified r7/r8): tp_w (f32) -> f16, alpha folded, per-lane
// fragment order. Fragment blocks of 512 f16 (one 32k x 16n MFMA B tile),
// f = ks*NT + nt; element lane*8+jj = W[k=ks*32+(lane>>4)*8+jj][n=nt*16+(lane&15)].
// ---------------------------------------------------------------------------
__global__ void w_prep(const float* __restrict__ tp_w, f16* __restrict__ wpre) {
    const int WOFF[11] = {0,16384,24576,28672,36864,40960,45056,47104,51200,52224,54272};
    const int UA[11]   = {64,32,16,64,32,32,16,64,16,32,16};
    const int NA[11]   = {64,64,64,32,32,32,32,16,16,16,16};
    const int L3A[11]  = {0,0,0,1,1,1,1,2,2,2,2};
    const float alph[3] = { 1.0f/sqrtf(448.0f), 1.0f/24.0f, 1.0f/sqrtf(512.0f) };
    int tid = threadIdx.x;
    for (int p = 0; p < 11; ++p) {
        int U = UA[p], N = NA[p], woff = WOFF[p];
        int NT = N/16;
        int size = U*4*N;
        float alpha = alph[L3A[p]];
        for (int j = tid; j < size; j += 256) {
            int f = j >> 9, r = j & 511;                // 512 f16 per fragment block
            int lane = r >> 3, jj = r & 7;              // lane 0..63
            int ks = f / NT, nt = f - ks*NT;
            int k = ks*32 + (lane>>4)*8 + jj;           // global (u*4+v) row
            int n = nt*16 + (lane&15);
            wpre[woff + j] = (f16)(tp_w[woff + k*N + n] * alpha);
        }
    }
}

// ---------------------------------------------------------------------------
// B-table build (for NT>1 groups only): B[row = e*NK+kk][u] with XOR granule
// swizzle: granule g (f16x2) stored at g ^ (row & (GR-1)). Spread per-granule
// over all 256 threads (cy recomputed per granule; small).
// ---------------------------------------------------------------------------
template<int l1, int l2, int l3>
__device__ __forceinline__ void build_B(
    int tid, int cgoff, f16* B,
    const f16* sN16, const float (*sY)[8], const float* sW3)
{
    constexpr int U  = (l1 == 1) ? 32 : 16;
    constexpr int NI = 2*l1 + 1, NJ = 2*l2 + 1, NK = 2*l3 + 1;
    constexpr int SEC = (l1 == 1) ? 64 : 160;
    constexpr int GR = U / 2;                    // f16x2 granules per row

    for (int idx = tid; idx < TE*NK*GR; idx += 256) {
        int row = idx / GR, g = idx - row*GR;
        int e = row / NK, kk = row - e*NK;
        float cyr[NI];
        #pragma unroll
        for (int i = 0; i < NI; ++i) {
            float c = 0.f;
            #pragma unroll
            for (int j = 0; j < NJ; ++j) {
                float yj = (l2 == 0) ? 1.f : ((l2 == 1) ? sY[e][j] : sY[e][3 + j]);
                c += sW3[cgoff + (i*NJ + j)*NK + kk] * yj;
            }
            cyr[i] = c;
        }
        const f16* nb = sN16 + e*NPAD + SEC + 2*g*NI;
        float b0 = 0.f, b1 = 0.f;
        #pragma unroll
        for (int i = 0; i < NI; ++i) {
            b0 += (float)nb[i]      * cyr[i];
            b1 += (float)nb[NI + i] * cyr[i];
        }
        *(f16x2*)(B + row*U + ((g ^ (row & (GR-1))) << 1)) = cvtpk(b0, b1);
    }
}

// ---------------------------------------------------------------------------
// Group-0 (l3=0, NK=1, NT=4) with FLIPPED task map: wave wv -> mt = wv&1,
// nt in {2*(wv>>1), 2*(wv>>1)+1}. A-fragment built ONCE per ks, shared by
// the wave's 2 MFMAs (only the W fragment differs).
// ---------------------------------------------------------------------------
__device__ __forceinline__ void mfma_000(
    int tid, const f16* __restrict__ wpre,
    const f16* sN16, const float* sW3, const f16x2 (*sWlPk)[6],
    f32x4 (&acc)[3])
{
    const int wv = tid >> 6, lane = tid & 63;
    const int ln = tid & 15, qt = (tid & 63) >> 4;
    const int mt = wv & 1, nt0 = (wv >> 1) * 2;
    const int e = mt*16 + ln;
    float c = sW3[0];
    f16x2 cy = cvtpk(c, c);
    f16x2 wl0 = sWlPk[e][0], wl1 = sWlPk[e][1];
    const f16* nb = sN16 + e*NPAD;               // SEC = 0
    const f16* wbase = wpre + (size_t)nt0*512 + lane*8;   // woff = 0, NT = 4
    #pragma unroll
    for (int ks = 0; ks < 8; ++ks) {
        f16x8 wf0 = *(const f16x8*)(wbase + (size_t)(ks*4)*512);
        f16x8 wf1 = *(const f16x8*)(wbase + (size_t)(ks*4 + 1)*512);
        int u0 = ks*8 + qt*2;
        f16x2 bh = *(const f16x2*)(nb + u0) * cy;
        f16x2 b00 = {bh[0], bh[0]}, b11 = {bh[1], bh[1]};
        f16x2 a01 = b00*wl0, a23 = b00*wl1, a45 = b11*wl0, a67 = b11*wl1;
        f16x8 af = {a01[0],a01[1],a23[0],a23[1],a45[0],a45[1],a67[0],a67[1]};
        acc[0] = __builtin_amdgcn_mfma_f32_16x16x32_f16(af, wf0, acc[0], 0, 0, 0);
        acc[1] = __builtin_amdgcn_mfma_f32_16x16x32_f16(af, wf1, acc[1], 0, 0, 0);
    }
}

template<int l1_, int l2_>   // paths 110 (1,1), 220 (2,2); l3=0
__device__ __forceinline__ void mfma_B_g0(
    int tid, int woff, const f16* __restrict__ wpre, const f16* B,
    const f16x2 (*sWlPk)[6], f32x4 (&acc)[3])
{
    constexpr int U  = (l1_ == 1) ? 32 : 16;
    constexpr int KS = U / 8;
    constexpr int GR = U / 2;
    const int wv = tid >> 6, lane = tid & 63;
    const int ln = tid & 15, qt = (tid & 63) >> 4;
    const int mt = wv & 1, nt0 = (wv >> 1) * 2;
    const int e = mt*16 + ln;                    // row = e (NK=1)
    f16x2 wl0 = sWlPk[e][l2_*2 + 0], wl1 = sWlPk[e][l2_*2 + 1];
    const f16* brow = B + e*U;
    const int msk = e & (GR - 1);
    const f16* wbase = wpre + woff + (size_t)nt0*512 + lane*8;
    #pragma unroll
    for (int ks = 0; ks < KS; ++ks) {
        f16x8 wf0 = *(const f16x8*)(wbase + (size_t)(ks*4)*512);
        f16x8 wf1 = *(const f16x8*)(wbase + (size_t)(ks*4 + 1)*512);
        int g = ks*4 + qt;
        f16x2 bh = *(const f16x2*)(brow + ((g ^ msk) << 1));
        f16x2 b00 = {bh[0], bh[0]}, b11 = {bh[1], bh[1]};
        f16x2 a01 = b00*wl0, a23 = b00*wl1, a45 = b11*wl0, a67 = b11*wl1;
        f16x8 af = {a01[0],a01[1],a23[0],a23[1],a45[0],a45[1],a67[0],a67[1]};
        acc[0] = __builtin_amdgcn_mfma_f32_16x16x32_f16(af, wf0, acc[0], 0, 0, 0);
        acc[1] = __builtin_amdgcn_mfma_f32_16x16x32_f16(af, wf1, acc[1], 0, 0, 0);
    }
}

// group-0 store (flipped map): task t -> nt = nt0+t, mt = wv&1, kk = 0.
__device__ __forceinline__ void store_g0(int tid, const f32x4 (&acc)[3], f16* sAcc16)
{
    int wv = tid >> 6, ln = tid & 15, qt = (tid & 63) >> 4;
    int mt = wv & 1, nt0 = (wv >> 1) * 2;
    #pragma unroll
    for (int t = 0; t < 2; ++t) {
        int ch = (nt0 + t)*16 + ln;              // OFF=0, NK=1
        #pragma unroll
        for (int r = 0; r < 4; ++r) {
            int e = mt*16 + qt*4 + r;
            sAcc16[e*240 + ch] = (f16)acc[t][r];
        }
    }
}

// ---------------------------------------------------------------------------
// Group-1 B consume (r8 task map: task = t*4+wv; nt = wv&1 shared; NK=3).
// ---------------------------------------------------------------------------
template<int l1_, int l2_>   // 101 (1,0), 121 (1,2), 211 (2,1)
__device__ __forceinline__ void mfma_B1(
    int tid, int woff, const f16* __restrict__ wpre, const f16* B,
    const f16x2 (*sWlPk)[6], f32x4 (&acc)[3])
{
    constexpr int U  = (l1_ == 1) ? 32 : 16;
    constexpr int KS = U / 8;
    constexpr int GR = U / 2;
    constexpr int NT = 2, NK = 3, NTASKS = 12;
    const int wv = tid >> 6, lane = tid & 63;
    const int ln = tid & 15, qt = (tid & 63) >> 4;
    const int ntw = wv & 1;

    const f16* browT[3];
    int mskT[3];
    f16x2 wl0T[3], wl1T[3];
    #pragma unroll
    for (int t = 0; t < 3; ++t) {
        int task = t*4 + wv;                     // < 12 always
        int mt = task / NT;
        int kk = mt >> 1;
        int e  = (mt & 1)*16 + ln;
        int row = e*NK + kk;
        browT[t] = B + row*U;
        mskT[t]  = row & (GR - 1);
        wl0T[t] = sWlPk[e][l2_*2 + 0];
        wl1T[t] = sWlPk[e][l2_*2 + 1];
    }
    const f16* wbase = wpre + woff + (size_t)ntw*512 + lane*8;
    #pragma unroll
    for (int ks = 0; ks < KS; ++ks) {
        f16x8 wf = *(const f16x8*)(wbase + (size_t)(ks*NT)*512);
        int g = ks*4 + qt;
        #pragma unroll
        for (int t = 0; t < 3; ++t) {
            f16x2 bh = *(const f16x2*)(browT[t] + ((g ^ mskT[t]) << 1));
            f16x2 b00 = {bh[0], bh[0]}, b11 = {bh[1], bh[1]};
            f16x2 a01 = b00*wl0T[t], a23 = b00*wl1T[t];
            f16x2 a45 = b11*wl0T[t], a67 = b11*wl1T[t];
            f16x8 af = {a01[0],a01[1],a23[0],a23[1],a45[0],a45[1],a67[0],a67[1]};
            acc[t] = __builtin_amdgcn_mfma_f32_16x16x32_f16(af, wf, acc[t], 0, 0, 0);
        }
    }
}

// ---------------------------------------------------------------------------
// l1 == 0 direct path (NI=1), r8 task map — paths 011, 022.
// ---------------------------------------------------------------------------
template<int l2, int l3>
__device__ __forceinline__ void mfma_l0(
    int tid, int woff, int cgoff,
    const f16* __restrict__ wpre,
    const f16* sN16, const float (*sY)[8], const float* sW3,
    const f16x2 (*sWlPk)[6],
    f32x4 (&acc)[3])
{
    constexpr int N  = (l3 == 0) ? 64 : (l3 == 1) ? 32 : 16;
    constexpr int NJ = 2*l2 + 1, NK = 2*l3 + 1;
    constexpr int M  = NK * TE;
    constexpr int KS = 8;                        // U = 64
    constexpr int NT = N / 16;
    constexpr int NTASKS = (M/16) * NT;
    constexpr int NW = (NTASKS + 3) / 4;

    const int wv = tid >> 6, lane = tid & 63;
    const int ln = tid & 15, qt = (tid & 63) >> 4;
    const int ntw = wv % NT;

    const f16* nbT[NW];
    f16x2 cyP[NW];
    f16x2 wl0T[NW], wl1T[NW];
    #pragma unroll
    for (int t = 0; t < NW; ++t) {
        int task = t*4 + wv;
        if (task < NTASKS) {
            int mt = task / NT;
            int kk = mt >> 1;
            int e  = (mt & 1)*16 + ln;
            float c = 0.f;
            #pragma unroll
            for (int j = 0; j < NJ; ++j) {
                float yj = (l2 == 0) ? 1.f : ((l2 == 1) ? sY[e][j] : sY[e][3 + j]);
                c += sW3[cgoff + j*NK + kk] * yj;
            }
            cyP[t] = cvtpk(c, c);
            wl0T[t] = sWlPk[e][l2*2 + 0];
            wl1T[t] = sWlPk[e][l2*2 + 1];
            nbT[t]  = sN16 + e*NPAD;             // SEC = 0
        }
    }

    const f16* wbase = wpre + woff + (size_t)ntw*512 + lane*8;
    #pragma unroll
    for (int ks = 0; ks < KS; ++ks) {
        f16x8 wf = *(const f16x8*)(wbase + (size_t)ks*NT*512);
        const int u0 = ks*8 + qt*2;
        #pragma unroll
        for (int t = 0; t < NW; ++t) {
            int task = t*4 + wv;
            if (task < NTASKS) {
                f16x2 n01 = *(const f16x2*)(nbT[t] + u0);
                f16x2 bh = n01 * cyP[t];
                f16x2 b00 = {bh[0], bh[0]}, b11 = {bh[1], bh[1]};
                f16x2 a01 = b00*wl0T[t], a23 = b00*wl1T[t];
                f16x2 a45 = b11*wl0T[t], a67 = b11*wl1T[t];
                f16x8 af = {a01[0],a01[1],a23[0],a23[1],a45[0],a45[1],a67[0],a67[1]};
                acc[t] = __builtin_amdgcn_mfma_f32_16x16x32_f16(af, wf, acc[t], 0, 0, 0);
            }
        }
    }
}

// ---------------------------------------------------------------------------
// Direct register-build path (r8-verified), used for group 2 (NT=1 — no
// duplication to remove): paths 202, 112, 222.
// ---------------------------------------------------------------------------
template<int l1, int l2, int l3>
__device__ __forceinline__ void path_direct(
    int tid, int woff, int cgoff,
    const f16* __restrict__ wpre,
    const f16* sN16, const float (*sY)[8], const float* sW3,
    const f16x2 (*sWlPk)[6],
    f32x4 (&acc)[3])
{
    constexpr int U  = (l1 == 0) ? 64 : (l1 == 1) ? 32 : 16;
    constexpr int N  = (l3 == 0) ? 64 : (l3 == 1) ? 32 : 16;
    constexpr int NI = 2*l1 + 1, NJ = 2*l2 + 1, NK = 2*l3 + 1;
    constexpr int M  = NK * TE;
    constexpr int SEC = (l1 == 0) ? 0 : (l1 == 1) ? 64 : 160;
    constexpr int KS = U / 8;
    constexpr int NT = N / 16;
    constexpr int NTASKS = (M/16) * NT;
    constexpr int NW = (NTASKS + 3) / 4;

    const int wv = tid >> 6, lane = tid & 63;
    const int ln = tid & 15, qt = (tid & 63) >> 4;
    const int ntw = wv % NT;

    const f16* nbT[NW];
    float cyT[NW][NI];
    f16x2 wl0T[NW], wl1T[NW];
    #pragma unroll
    for (int t = 0; t < NW; ++t) {
        int task = t*4 + wv;
        if (task < NTASKS) {
            int mt = task / NT;
            int kk = mt >> 1;
            int e  = (mt & 1)*16 + ln;
            #pragma unroll
            for (int i = 0; i < NI; ++i) {
                float c = 0.f;
                #pragma unroll
                for (int j = 0; j < NJ; ++j) {
                    float yj = (l2 == 0) ? 1.f : ((l2 == 1) ? sY[e][j] : sY[e][3 + j]);
                    c += sW3[cgoff + (i*NJ + j)*NK + kk] * yj;
                }
                cyT[t][i] = c;
            }
            wl0T[t] = sWlPk[e][l2*2 + 0];
            wl1T[t] = sWlPk[e][l2*2 + 1];
            nbT[t]  = sN16 + e*NPAD + SEC;
        }
    }

    const f16* wbase = wpre + woff + (size_t)ntw*512 + lane*8;
    #pragma unroll
    for (int ks = 0; ks < KS; ++ks) {
        f16x8 wf = *(const f16x8*)(wbase + (size_t)ks*NT*512);
        const int u0 = ks*8 + qt*2;
        #pragma unroll
        for (int t = 0; t < NW; ++t) {
            int task = t*4 + wv;
            if (task < NTASKS) {
                float b0 = 0.f, b1 = 0.f;
                #pragma unroll
                for (int i = 0; i < NI; ++i) {
                    b0 += (float)nbT[t][u0*NI + i]      * cyT[t][i];
                    b1 += (float)nbT[t][u0*NI + NI + i] * cyT[t][i];
                }
                f16 b0h = (f16)b0, b1h = (f16)b1;
                f16x2 b00 = {b0h, b0h}, b11 = {b1h, b1h};
                f16x2 a01 = b00*wl0T[t], a23 = b00*wl1T[t];
                f16x2 a45 = b11*wl0T[t], a67 = b11*wl1T[t];
                f16x8 af = {a01[0],a01[1],a23[0],a23[1],a45[0],a45[1],a67[0],a67[1]};
                acc[t] = __builtin_amdgcn_mfma_f32_16x16x32_f16(af, wf, acc[t], 0, 0, 0);
            }
        }
    }
}

// write a group's accumulators into the f16 staging tile (r8 task map)
// D layout (verified r5/r7/r8): col = lane&15, row = 4*(lane>>4) + reg
template<int NK, int NT, int NTASKS, int OFF>
__device__ __forceinline__ void store_group(int tid, const f32x4 (&acc)[3], f16* sAcc16)
{
    int wv = tid >> 6;
    int ln = tid & 15, qt = (tid & 63) >> 4;
    #pragma unroll
    for (int t = 0; t < 3; ++t) {
        int task = t*4 + wv;
        if (task < NTASKS) {
            int mt = task / NT, nt = task % NT;
            int kk = mt >> 1;
            int e0 = (mt & 1) * 16;
            #pragma unroll
            for (int r = 0; r < 4; ++r) {
                int e = e0 + qt*4 + r;
                sAcc16[e*240 + OFF + (nt*16 + ln)*NK + kk] = (f16)acc[t][r];
            }
        }
    }
}

__global__ __launch_bounds__(256, 4)
void edge_main(const float* __restrict__ node_feat,
               const int*   __restrict__ edge_src,
               const float* __restrict__ edge_vec,
               const float* __restrict__ maskp,
               const float* __restrict__ mlp_w1, const float* __restrict__ mlp_b1,
               const float* __restrict__ mlp_w2, const float* __restrict__ mlp_b2,
               const f16*   __restrict__ wpre,
               const float* __restrict__ w3j,
               float* __restrict__ out)
{
    __shared__ __align__(16) f16 sN16[TE*NPAD];     // 15.2KB node rows
    __shared__ __align__(16) f16 sAcc16[TE*240];    // 15.4KB result staging
    __shared__ __align__(16) f16 Bls[3072];         // 6KB B-tables (swizzled)
    __shared__ float sW3[364];
    __shared__ float sY[TE][8];
    __shared__ f16x2 sWlPk[TE][6];

    // phase-0 scratch aliases onto sAcc16 (10.1KB used; dead before store_group)
    float* sRbf  = (float*)sAcc16;          // [TE][32]  4KB
    float* sH    = sRbf + TE*32;            // [TE][32]  4KB
    float* sWl   = sH   + TE*32;            // [TE][12]  1.5KB
    float* sR    = sWl  + TE*12;            // [TE]
    float* sRb2  = sR   + TE;               // [TE]
    float* sMask = sRb2 + TE;               // [TE]
    int*   sSrc  = (int*)(sMask + TE);      // [TE]

    int tid = threadIdx.x;
    long eg0 = (long)blockIdx.x * TE;

    // ---- phase 0a: per-edge geometry -------------------------------------
    if (tid < TE) {
        long eg = eg0 + tid;
        float vx = edge_vec[eg*3 + 0], vy = edge_vec[eg*3 + 1], vz = edge_vec[eg*3 + 2];
        float rn = sqrtf(vx*vx + vy*vy + vz*vz);
        float r  = fmaxf(rn, 1e-12f);
        float inv = 1.0f / r;
        float x = vx*inv, y = vy*inv, z = vz*inv;
        sR[tid] = r;
        float rb = 0.5f * (cosf(r * 3.14159265358979323846f / 5.0f) + 1.0f);
        sRb2[tid] = (r < 5.0f) ? rb*rb : 0.0f;
        sMask[tid] = maskp[eg];
        sSrc[tid]  = edge_src[eg];
        const float s3 = sqrtf(3.0f), s5 = sqrtf(5.0f), s15 = sqrtf(15.0f);
        sY[tid][0] = s3*x; sY[tid][1] = s3*y; sY[tid][2] = s3*z;
        sY[tid][3] = s15*x*z;
        sY[tid][4] = s15*x*y;
        sY[tid][5] = s5*(y*y - 0.5f*(x*x + z*z));
        sY[tid][6] = s15*y*z;
        sY[tid][7] = 0.5f*s15*(z*z - x*x);
    }
    for (int t = tid; t < 363; t += 256) sW3[t] = w3j[t];   // grid-stride (363 > 256)
    __syncthreads();

    // ---- phase 0b: gather node rows (f32 float4 -> f16 LDS) + RBF --------
    {
        float em5  = expf(-5.0f);
        float step = (1.0f - em5) / 31.0f;
        float beta = 256.0f / ((1.0f - em5) * (1.0f - em5));
        for (int idx = tid; idx < TE*32; idx += 256) {
            int e = idx >> 5, j = idx & 31;
            float mean = em5 + step * j;
            float d = expf(-sR[e]) - mean;
            sRbf[e*32 + j] = sRb2[e] * expf(-beta * d * d);
        }
    }
    for (int idx = tid; idx < TE*60; idx += 256) {
        int e = idx / 60, q = idx - e*60;
        f32x4 v = *(const f32x4*)(node_feat + (long)sSrc[e]*NODE_DIM + q*4);
        f16x4 h = {(f16)v.x, (f16)v.y, (f16)v.z, (f16)v.w};
        *(f16x4*)&sN16[e*NPAD + q*4] = h;
    }
    __syncthreads();

    // ---- phase 0c: per-l MLP -> edge weights wl (mask folded in) ---------
    for (int l = 0; l < 3; ++l) {
        for (int idx = tid; idx < TE*32; idx += 256) {
            int e = idx >> 5, j = idx & 31;
            float zacc = mlp_b1[l*32 + j];
            #pragma unroll 8
            for (int rr = 0; rr < 32; ++rr) zacc += sRbf[e*32 + rr] * mlp_w1[(l*32 + rr)*32 + j];
            sH[e*32 + j] = zacc / (1.0f + expf(-zacc));   // silu
        }
        __syncthreads();
        for (int idx = tid; idx < TE*4; idx += 256) {
            int e = idx >> 2, v = idx & 3;
            float zacc = mlp_b2[l*4 + v];
            #pragma unroll 8
            for (int j = 0; j < 32; ++j) zacc += sH[e*32 + j] * mlp_w2[(l*32 + j)*4 + v];
            sWl[e*12 + l*4 + v] = zacc;
        }
        __syncthreads();
    }
    // pack (wl * mask) as f16 pairs
    for (int idx = tid; idx < TE*6; idx += 256) {
        int e = idx / 6, h = idx - e*6;
        int l = h >> 1, vh = h & 1;
        float m = sMask[e];
        f16x2 p = {(f16)(sWl[e*12 + l*4 + vh*2] * m), (f16)(sWl[e*12 + l*4 + vh*2 + 1] * m)};
        sWlPk[e][h] = p;
    }
    __syncthreads();    // scratch (aliased on sAcc16) dead from here

    f32x4 acc[3];

    // ---- group l3=0 (flipped map): 000 direct; 110, 220 via B ------------
    build_B<1,1,0>(tid,   1, Bls,        sN16, sY, sW3);   // 32x32 = 1024 f16
    build_B<2,2,0>(tid,  10, Bls + 1024, sN16, sY, sW3);   // 32x16 = 512 f16
    __syncthreads();
    #pragma unroll
    for (int t = 0; t < 3; ++t) acc[t] = {0.f, 0.f, 0.f, 0.f};
    mfma_000(tid, wpre, sN16, sW3, sWlPk, acc);
    mfma_B_g0<1,1>(tid, 16384, wpre, Bls,        sWlPk, acc);
    mfma_B_g0<2,2>(tid, 24576, wpre, Bls + 1024, sWlPk, acc);
    store_g0(tid, acc, sAcc16);
    __syncthreads();    // Bls consumed

    // ---- group l3=1 (r8 map): 011 direct; 101, 121, 211 via sequential B -
    build_B<1,0,1>(tid,  44, Bls, sN16, sY, sW3);          // 96x32 = 3072 f16
    __syncthreads();
    #pragma unroll
    for (int t = 0; t < 3; ++t) acc[t] = {0.f, 0.f, 0.f, 0.f};
    mfma_l0<1,1>(tid, 28672,  35, wpre, sN16, sY, sW3, sWlPk, acc);
    mfma_B1<1,0>(tid, 36864, wpre, Bls, sWlPk, acc);       // 101
    __syncthreads();
    build_B<1,2,1>(tid,  53, Bls, sN16, sY, sW3);          // 96x32
    __syncthreads();
    mfma_B1<1,2>(tid, 40960, wpre, Bls, sWlPk, acc);       // 121
    __syncthreads();
    build_B<2,1,1>(tid,  98, Bls, sN16, sY, sW3);          // 96x16 = 1536 f16
    __syncthreads();
    mfma_B1<2,1>(tid, 45056, wpre, Bls, sWlPk, acc);       // 211
    store_group<3, 2, 12, 64>(tid, acc, sAcc16);

    // ---- group l3=2 (NT=1, no duplication -> all direct, r8) -------------
    #pragma unroll
    for (int t = 0; t < 3; ++t) acc[t] = {0.f, 0.f, 0.f, 0.f};
    mfma_l0<2,2>(tid, 47104, 143, wpre, sN16, sY, sW3, sWlPk, acc);
    path_direct<2,0,2>(tid, 51200, 168, wpre, sN16, sY, sW3, sWlPk, acc);
    path_direct<1,1,2>(tid, 52224, 193, wpre, sN16, sY, sW3, sWlPk, acc);
    path_direct<2,2,2>(tid, 54272, 238, wpre, sN16, sY, sW3, sWlPk, acc);
    store_group<5, 1, 10, 160>(tid, acc, sAcc16);

    __syncthreads();

    // ---- single coalesced nontemporal output pass (alpha/mask pre-folded) -
    for (int idx = tid; idx < TE*30; idx += 256) {
        int e = idx / 30, q = idx - e*30;        // q = half8 index within row
        f16x8 v = *(const f16x8*)&sAcc16[e*240 + q*8];
        f32x4 lo = {(float)v[0], (float)v[1], (float)v[2], (float)v[3]};
        f32x4 hi = {(float)v[4], (float)v[5], (float)v[6], (float)v[7]};
        float* dst = out + (eg0 + e)*NODE_DIM + q*8;
        __builtin_nontemporal_store(lo, (f32x4*)dst);
        __builtin_nontemporal_store(hi, (f32x4*)(dst + 4));
    }
}

// ---------------------------------------------------------------------------
// launch
// ---------------------------------------------------------------------------
extern "C" void kernel_launch(void* const* d_in, const int* in_sizes, int n_in,
                              void* d_out, int out_size, void* d_ws, size_t ws_size,
                              hipStream_t stream)
{
    const float* node_feat = (const float*)d_in[0];
    const int*   edge_idx  = (const int*)  d_in[1];
    const float* edge_vec  = (const float*)d_in[2];
    const float* maskp     = (const float*)d_in[3];
    const float* mlp_w1    = (const float*)d_in[4];
    const float* mlp_b1    = (const float*)d_in[5];
    const float* mlp_w2    = (const float*)d_in[6];
    const float* mlp_b2    = (const float*)d_in[7];
    const float* tp_w      = (const float*)d_in[8];
    float* out  = (float*)d_out;
    float* w3j  = (float*)d_ws;
    f16*   wpre = (f16*)((char*)d_ws + 2048);     // 110592 B of f16 weights

    int E = in_sizes[3];                 // = N_EDGES = 800000 (divisible by TE)
    const int* edge_src = edge_idx;      // row 0 of (2, E)

    hipLaunchKernelGGL(w3j_init, dim3(1), dim3(512), 0, stream, w3j);
    hipLaunchKernelGGL(w_prep,   dim3(1), dim3(256), 0, stream, tp_w, wpre);
    hipLaunchKernelGGL(edge_main, dim3(E / TE), dim3(256), 0, stream,
                       node_feat, edge_src, edge_vec, maskp,
                       mlp_w1, mlp_b1, mlp_w2, mlp_b2, wpre, w3j, out);
}